// Round 6
// baseline (728.800 us; speedup 1.0000x reference)
//
#include <hip/hip_runtime.h>
#include <stdint.h>

#define BB 256      // batch
#define TT 200      // timesteps
#define INN 1568    // inputs
#define OO 100      // outputs
#define PAIRS 784   // INN/2
#define NHALF 12800 // (BB*OO)/2
#define NBLK 240    // co-resident grid (1 block/CU)
#define ROWSTRIDE (4 * INN)

typedef unsigned long long u64;
typedef __attribute__((ext_vector_type(4))) int v4i;

// async global->LDS (16 B/lane); dest arg is this lane's slot (base+lane*16)
typedef const __attribute__((address_space(1))) uint32_t* gas_p;
typedef __attribute__((address_space(3))) uint32_t* las_p;
#define GLD16(g, l) __builtin_amdgcn_global_load_lds((gas_p)(g), (las_p)(l), 16, 0, 0)

// ---------------- threefry2x32 (JAX-compatible) ----------------
__device__ __forceinline__ void tf_round(uint32_t& x0, uint32_t& x1, int r) {
    x0 += x1;
    x1 = (x1 << r) | (x1 >> (32 - r));
    x1 ^= x0;
}

__device__ __forceinline__ void threefry(uint32_t k0, uint32_t k1,
                                         uint32_t x0, uint32_t x1,
                                         uint32_t& o0, uint32_t& o1) {
    uint32_t k2 = k0 ^ k1 ^ 0x1BD11BDAu;
    x0 += k0; x1 += k1;
    tf_round(x0,x1,13); tf_round(x0,x1,15); tf_round(x0,x1,26); tf_round(x0,x1,6);
    x0 += k1; x1 += k2 + 1u;
    tf_round(x0,x1,17); tf_round(x0,x1,29); tf_round(x0,x1,16); tf_round(x0,x1,24);
    x0 += k2; x1 += k0 + 2u;
    tf_round(x0,x1,13); tf_round(x0,x1,15); tf_round(x0,x1,26); tf_round(x0,x1,6);
    x0 += k0; x1 += k1 + 3u;
    tf_round(x0,x1,17); tf_round(x0,x1,29); tf_round(x0,x1,16); tf_round(x0,x1,24);
    x0 += k1; x1 += k2 + 4u;
    tf_round(x0,x1,13); tf_round(x0,x1,15); tf_round(x0,x1,26); tf_round(x0,x1,6);
    o0 = x0 + k2; o1 = x1 + k0 + 5u;
}

// ---------------- LDS: phases time-separated by gridsync ----------------
struct DSM {                       // phase D (block-shared rings)
    u64 rowsR[32][128];            // [t&31][k*16+pl]           32 KB
    u64 winR[8][128];              // [t&7][o-local*4+wb]        8 KB
    u64 postR[8][128];             //                            8 KB
    uint32_t cntR[8][32];          // [t&7][o-local]             1 KB
    u64 potC[2][16][10];           // [buf][pl][k] (80B stride)  2.5 KB
    u64 ltpC[2][16][10];           //                            2.5 KB
};
struct FwSM { uint32_t wl32[TT * 65]; int fwl[BB]; };   // phase B, 53 KB
union SMem { DSM d; FwSM w; };

__device__ __forceinline__ void gridsync(uint32_t* c, uint32_t target) {
    __syncthreads();
    if (threadIdx.x == 0) {
        __threadfence();   // release stores (agent scope)
        __hip_atomic_fetch_add(c, 1u, __ATOMIC_ACQ_REL, __HIP_MEMORY_SCOPE_AGENT);
        while (__hip_atomic_load(c, __ATOMIC_ACQUIRE, __HIP_MEMORY_SCOPE_AGENT)
               < target)
            __builtin_amdgcn_s_sleep(8);
        __threadfence();
    }
    __syncthreads();
}

__global__ __launch_bounds__(512, 1) void k_mono(
        const int* __restrict__ x,
        const float* __restrict__ L0,
        const float* __restrict__ p0arr,
        uint32_t* __restrict__ syncc,
        uint8_t* __restrict__ widx,
        uint32_t* __restrict__ cntg,
        u64* __restrict__ winbits,
        u64* __restrict__ postbits,
        u64* __restrict__ bitB,
        float* __restrict__ outL,
        float* __restrict__ outp) {
    __shared__ SMem sm;
    __shared__ uint32_t smclaim;
    const int tid = threadIdx.x;
    const int bid = blockIdx.x;

    // ====== phase A+B (blocks 0..99) concurrent with C start (100..239) ====
    if (bid < 100) {
        {   // A: winners for t = 2*bid, 2*bid+1 (512 = 2t x 256b)
            int idx = bid * 512 + tid;
            int t = idx >> 8, b = idx & 255;
            uint32_t fk0, fk1;
            threefry(0u, 42u, 0u, (uint32_t)t, fk0, fk1);  // fold_in(key(42), t)
            uint32_t bestkey = 0u;
            int bo = 0;
            int nbase = b * OO;
            for (int o = 0; o < OO; ++o) {
                uint32_t n = (uint32_t)(nbase + o);
                uint32_t lo = (n < NHALF) ? n : n - NHALF;
                uint32_t v0, v1;
                threefry(fk0, fk1, lo, lo + NHALF, v0, v1);
                uint32_t bits = (n < NHALF) ? v0 : v1;
                uint32_t key = bits >> 9;   // monotone proxy for gumbel
                if (key > bestkey) { bestkey = key; bo = o; }
            }
            widx[idx] = (uint8_t)bo;
        }
        gridsync(&syncc[0], 100u);      // partial: only A/B blocks
        {   // B: fwpost for o = bid
            const uint32_t* wsrc = (const uint32_t*)widx;
            for (int g = tid; g < TT * 64; g += 512)
                sm.w.wl32[(g >> 6) * 65 + (g & 63)] = wsrc[g];
            __syncthreads();
            int o = bid;
            if (tid < 64) {
                int f0 = 255, f1 = 255, f2 = 255, f3 = 255;
                for (int t = 0; t < TT; ++t) {
                    uint32_t w4 = sm.w.wl32[t * 65 + tid];
                    if (((w4      ) & 255u) == (uint32_t)o && f0 == 255) f0 = t;
                    if (((w4 >>  8) & 255u) == (uint32_t)o && f1 == 255) f1 = t;
                    if (((w4 >> 16) & 255u) == (uint32_t)o && f2 == 255) f2 = t;
                    if (((w4 >> 24) & 255u) == (uint32_t)o && f3 == 255) f3 = t;
                }
                sm.w.fwl[4 * tid + 0] = f0; sm.w.fwl[4 * tid + 1] = f1;
                sm.w.fwl[4 * tid + 2] = f2; sm.w.fwl[4 * tid + 3] = f3;
            }
            __syncthreads();
            if (tid < TT) {
                int t = tid;
                u64 wbA[4], pbA[4];
                uint32_t c = 0;
                #pragma unroll
                for (int k = 0; k < 4; ++k) {
                    u64 wacc = 0, pacc = 0;
                    for (int q2 = 0; q2 < 16; ++q2) {
                        uint32_t w4 = sm.w.wl32[t * 65 + k * 16 + q2];
                        #pragma unroll
                        for (int j = 0; j < 4; ++j) {
                            int bl = q2 * 4 + j;
                            bool win = (((w4 >> (8 * j)) & 255u) == (uint32_t)o);
                            c += win ? 1u : 0u;
                            bool post = (sm.w.fwl[k * 64 + q2 * 4 + j] < t) && !win;
                            u64 bit = 1ull << bl;
                            if (win)  wacc |= bit;
                            if (post) pacc |= bit;
                        }
                    }
                    wbA[k] = wacc; pbA[k] = pacc;
                }
                size_t base = (size_t)(t * OO + o) * 4;
                #pragma unroll
                for (int k = 0; k < 4; ++k) {
                    winbits[base + k] = wbA[k];
                    postbits[base + k] = pbA[k];
                }
                cntg[t * OO + o] = c;
            }
            __syncthreads();
        }
    }

    // ====== phase C: bit-pack, atomic queue (C-blocks start immediately) ===
    {
        const v4i* xp = (const v4i*)x;
        for (;;) {
            __syncthreads();
            if (tid == 0)
                smclaim = __hip_atomic_fetch_add(&syncc[2], 1u, __ATOMIC_RELAXED,
                                                 __HIP_MEMORY_SCOPE_AGENT);
            __syncthreads();
            uint32_t u = smclaim;
            if (u >= 200u) break;
            int wb = u & 3, tc = u >> 2;
            u64 acc[4][4];
            #pragma unroll
            for (int q = 0; q < 4; ++q)
                #pragma unroll
                for (int c = 0; c < 4; ++c) acc[q][c] = 0;
            bool x4 = (tid < 32);          // 1568 = 3*512 + 32
            for (int blb = 0; blb < 64; blb += 4) {
                v4i v[4][3];
                v4i vt[4];
                #pragma unroll
                for (int s4 = 0; s4 < 4; ++s4) {
                    size_t base = ((size_t)((wb * 64 + blb + s4) * TT + tc * 4)) * 392;
                    #pragma unroll
                    for (int q = 0; q < 3; ++q)
                        v[s4][q] = __builtin_nontemporal_load(&xp[base + tid + q * 512]);
                    if (x4)
                        vt[s4] = __builtin_nontemporal_load(&xp[base + tid + 1536]);
                }
                #pragma unroll
                for (int s4 = 0; s4 < 4; ++s4) {
                    u64 bit = 1ull << (blb + s4);
                    #pragma unroll
                    for (int q = 0; q < 3; ++q) {
                        if (v[s4][q].x) acc[q][0] |= bit;
                        if (v[s4][q].y) acc[q][1] |= bit;
                        if (v[s4][q].z) acc[q][2] |= bit;
                        if (v[s4][q].w) acc[q][3] |= bit;
                    }
                    if (x4) {
                        if (vt[s4].x) acc[3][0] |= bit;
                        if (vt[s4].y) acc[3][1] |= bit;
                        if (vt[s4].z) acc[3][2] |= bit;
                        if (vt[s4].w) acc[3][3] |= bit;
                    }
                }
            }
            #pragma unroll
            for (int q = 0; q < 4; ++q) {
                if (q == 3 && !x4) continue;
                int p = tid + q * 512;
                int tp = (p >= 1176) ? 3 : (p >= 784) ? 2 : (p >= 392) ? 1 : 0;
                int iq = p - tp * 392;
                u64* dst = bitB + ((size_t)((tc * 4 + tp) * 4 + wb)) * INN + iq * 4;
                dst[0] = acc[q][0]; dst[1] = acc[q][1];
                dst[2] = acc[q][2]; dst[3] = acc[q][3];
            }
        }
    }
    gridsync(&syncc[1], (uint32_t)NBLK);

    // ====== phase D: block-shared ring chains ==============================
    // 196 blocks x (16 pairs x 25 outputs), 1 cell/thread (400 chain thr).
    // Wave 7 = loader: fills block-shared rings via global_load_lds, 3 groups
    // (6 t) ahead, counted vmcnt(16); one raw s_barrier per t. Rows/win/post
    // each loaded ONCE per block: traffic 210MB -> ~103MB vs per-wave rings.
    if (bid >= 197) return;
    if (bid == 196) {                           // ---- prior chain ----
        if (tid >= 64) return;
        int l = tid;
        bool has2 = (l + 64) < OO;
        float pa = p0arr[l];
        float pb = has2 ? p0arr[l + 64] : -1e30f;
        auto norm = [&]() {
            pa = fminf(fmaxf(pa, -5.0f), 0.0f);
            if (has2) pb = fminf(fmaxf(pb, -5.0f), 0.0f);
            float mx = has2 ? fmaxf(pa, pb) : pa;
            #pragma unroll
            for (int s = 32; s > 0; s >>= 1) mx = fmaxf(mx, __shfl_xor(mx, s, 64));
            float smv = expf(pa - mx) + (has2 ? expf(pb - mx) : 0.0f);
            #pragma unroll
            for (int s = 32; s > 0; s >>= 1) smv += __shfl_xor(smv, s, 64);
            float lse = logf(smv) + mx;
            pa -= lse;
            if (has2) pb -= lse;
        };
        norm();
        uint32_t na = cntg[l];
        uint32_t nb = has2 ? cntg[l + 64] : 0u;
        for (int t = 0; t < TT; ++t) {
            float ca = (float)na, cb = (float)nb;
            if (t < TT - 1) {
                na = cntg[(t + 1) * OO + l];
                nb = has2 ? cntg[(t + 1) * OO + l + 64] : 0u;
            }
            float eta = 0.001f / (float)(t + 1);
            float wma = ca * (1.0f / 256.0f);
            pa += eta * ((-5.0f * pa - 1.0f) * wma - (1.0f - wma));
            if (has2) {
                float wmb = cb * (1.0f / 256.0f);
                pb += eta * ((-5.0f * pb - 1.0f) * wmb - (1.0f - wmb));
            }
            norm();
        }
        outp[l] = pa;
        if (has2) outp[l + 64] = pb;
        return;
    }

    const int og = bid / 49, pg = bid % 49;     // 4 og x 49 pg = 196
    const int o0 = og * 25, p0 = pg * 16;
    const int pl = tid & 15, olx = tid >> 4;    // olx 0..31
    const bool isChain = (tid < 400);           // olx < 25
    const int o  = o0 + olx;
    const int i0 = p0 + pl, i1 = i0 + PAIRS;
    const int wave = tid >> 6, ll = tid & 63;
    const bool isLoader = (wave == 7);

    // loader per-lane global sources
    const int wk0 = ll >> 3, wpl0 = (ll & 7) * 2;
    const u64* rowg = bitB + (size_t)((wk0 & 3) * INN + (wk0 >> 2) * PAIRS
                                      + p0 + wpl0);
    auto issue = [&](int G) {
        #pragma unroll
        for (int h = 0; h < 2; ++h) {
            int s = 2 * G + h;
            int rr = (s < TT) ? s : (TT - 1);
            GLD16(rowg + (size_t)rr * ROWSTRIDE, (las_p)&sm.d.rowsR[s & 31][2 * ll]);
            if (ll < 50) {
                GLD16(winbits + ((size_t)rr * OO + o0) * 4 + 2 * ll,
                      (las_p)&sm.d.winR[s & 7][2 * ll]);
                GLD16(postbits + ((size_t)rr * OO + o0) * 4 + 2 * ll,
                      (las_p)&sm.d.postR[s & 7][2 * ll]);
            }
            if (ll < 7)
                GLD16(cntg + (size_t)rr * OO + o0 + 4 * ll,
                      (las_p)&sm.d.cntR[s & 7][4 * ll]);
        }
    };

    // ---- prologue: groups 0..2 (t 0..5); build potC[0]; init chains ----
    if (isLoader) {
        issue(0); issue(1); issue(2);
        asm volatile("s_waitcnt vmcnt(0)" ::: "memory");
    }
    __builtin_amdgcn_s_barrier();
    if (tid < 128) {
        int k = tid >> 4, plq = tid & 15;
        u64 r0 = sm.d.rowsR[0][k * 16 + plq];   // rows -10..0 all clamp to 0
        sm.d.potC[0][plq][k] = r0;
        sm.d.ltpC[0][plq][k] = r0;
    }
    float a = -1.0f, b2 = -1.0f;
    if (isChain) {
        a  = L0[(size_t)i0 * OO + o];
        b2 = L0[(size_t)i1 * OO + o];
        a  = fminf(fmaxf(a,  -5.0f), 0.0f);
        b2 = fminf(fmaxf(b2, -5.0f), 0.0f);
        float m = fmaxf(a, b2), mn = fminf(a, b2);
        float lse = __logf(1.0f + __expf(mn - m)) + m;
        a -= lse; b2 -= lse;
    }
    asm volatile("s_waitcnt lgkmcnt(0)" ::: "memory");
    __builtin_amdgcn_s_barrier();

    for (int t = 0; t < TT; ++t) {
        int cur = t & 1, nxt = cur ^ 1;
        if (isLoader && (t & 1) == 0) issue(t / 2 + 3);   // 3 groups ahead
        if (isChain) {
            const u64* W = &sm.d.winR[t & 7][olx * 4];
            const u64* S = &sm.d.postR[t & 7][olx * 4];
            const u64* P = sm.d.potC[cur][pl];
            const u64* Q = sm.d.ltpC[cur][pl];
            float cw = (float)sm.d.cntR[t & 7][olx];
            float lt0 = (float)(__popcll(Q[0]&W[0]) + __popcll(Q[1]&W[1])
                              + __popcll(Q[2]&W[2]) + __popcll(Q[3]&W[3]));
            float lt1 = (float)(__popcll(Q[4]&W[0]) + __popcll(Q[5]&W[1])
                              + __popcll(Q[6]&W[2]) + __popcll(Q[7]&W[3]));
            float pp0 = (float)(__popcll(P[0]&S[0]) + __popcll(P[1]&S[1])
                              + __popcll(P[2]&S[2]) + __popcll(P[3]&S[3]));
            float pp1 = (float)(__popcll(P[4]&S[0]) + __popcll(P[5]&S[1])
                              + __popcll(P[6]&S[2]) + __popcll(P[7]&S[3]));
            float eta = 0.001f / (float)(t + 1);
            float dw0 = (5.0f * __expf(-a)  - 1.0f) * (lt0 * (1.0f/256.0f))
                      + (cw - lt0 - pp0) * (1.0f/256.0f);
            float dw1 = (5.0f * __expf(-b2) - 1.0f) * (lt1 * (1.0f/256.0f))
                      + (cw - lt1 - pp1) * (1.0f/256.0f);
            a  += eta * dw0;
            b2 += eta * dw1;
            a  = fminf(fmaxf(a,  -5.0f), 0.0f);
            b2 = fminf(fmaxf(b2, -5.0f), 0.0f);
            float m = fmaxf(a, b2), mn = fminf(a, b2);
            float lse = __logf(1.0f + __expf(mn - m)) + m;
            a -= lse; b2 -= lse;
        }
        if (tid < 128 && t + 1 < TT) {          // build window for t+1
            int k = tid >> 4, plq = tid & 15;
            int e = k * 16 + plq;
            u64 acc = 0;
            #pragma unroll
            for (int j = 9; j >= 0; --j) {      // rows t+1-9 .. t+1 (SIGMA=10)
                int rr = t + 1 - j; if (rr < 0) rr = 0;   // OR-idempotent clamp
                acc |= sm.d.rowsR[rr & 31][e];
            }
            int rm = t + 1 - 10; if (rm < 0) rm = 0;
            u64 v10 = sm.d.rowsR[rm & 31][e];
            sm.d.potC[nxt][plq][k] = acc;
            sm.d.ltpC[nxt][plq][k] = acc | v10;
        }
        if (isLoader)
            asm volatile("s_waitcnt vmcnt(16) lgkmcnt(0)" ::: "memory");
        else
            asm volatile("s_waitcnt lgkmcnt(0)" ::: "memory");
        __builtin_amdgcn_s_barrier();
    }
    if (isChain) {
        outL[(size_t)i0 * OO + o] = a;
        outL[(size_t)i1 * OO + o] = b2;
    }
}

extern "C" void kernel_launch(void* const* d_in, const int* in_sizes, int n_in,
                              void* d_out, int out_size, void* d_ws, size_t ws_size,
                              hipStream_t stream) {
    const int*   x  = (const int*)d_in[0];
    const float* L0 = (const float*)d_in[1];
    const float* p0 = (const float*)d_in[2];
    float* out = (float*)d_out;

    char* ws = (char*)d_ws;
    size_t off = 0;
    auto alloc = [&](size_t bytes) -> void* {
        off = (off + 255) & ~(size_t)255;
        void* p = ws + off;
        off += bytes;
        return p;
    };
    uint32_t* syncc    = (uint32_t*)alloc(256);      // [0] AB-sync,[1] full,[2] C-queue
    uint8_t*  widx     = (uint8_t*) alloc((size_t)TT * BB);
    uint32_t* cntg     = (uint32_t*)alloc((size_t)TT * OO * 4);
    u64*      winbits  = (u64*)     alloc((size_t)TT * OO * 4 * 8);
    u64*      postbits = (u64*)     alloc((size_t)TT * OO * 4 * 8);
    u64*      bitB     = (u64*)     alloc((size_t)TT * 4 * INN * 8);
    (void)ws_size;

    hipMemsetAsync(syncc, 0, 256, stream);   // zero sync/queue counters
    hipLaunchKernelGGL(k_mono, dim3(NBLK), dim3(512), 0, stream,
                       x, L0, p0, syncc, widx, cntg, winbits, postbits, bitB,
                       out, out + (size_t)INN * OO);
}

// Round 7
// 685.543 us; speedup vs baseline: 1.0631x; 1.0631x over previous
//
#include <hip/hip_runtime.h>
#include <stdint.h>

#define BB 256      // batch
#define TT 200      // timesteps
#define INN 1568    // inputs
#define OO 100      // outputs
#define PAIRS 784   // INN/2
#define NHALF 12800 // (BB*OO)/2
#define NBLK 240    // co-resident grid (1 block/CU)
#define UNITS 686   // 98 pair-groups x 7 o-groups (chain wave-units)
#define ROWSTRIDE (4 * INN)

typedef unsigned long long u64;
typedef __attribute__((ext_vector_type(4))) int v4i;

// async global->LDS (16 B/lane); dest = wave-uniform base + lane*16
typedef const __attribute__((address_space(1))) uint32_t* gas_p;
typedef __attribute__((address_space(3))) uint32_t* las_p;
#define GLD16(g, l) __builtin_amdgcn_global_load_lds((gas_p)(g), (las_p)(l), 16, 0, 0)

// ---------------- threefry2x32 (JAX-compatible) ----------------
__device__ __forceinline__ void tf_round(uint32_t& x0, uint32_t& x1, int r) {
    x0 += x1;
    x1 = (x1 << r) | (x1 >> (32 - r));
    x1 ^= x0;
}

__device__ __forceinline__ void threefry(uint32_t k0, uint32_t k1,
                                         uint32_t x0, uint32_t x1,
                                         uint32_t& o0, uint32_t& o1) {
    uint32_t k2 = k0 ^ k1 ^ 0x1BD11BDAu;
    x0 += k0; x1 += k1;
    tf_round(x0,x1,13); tf_round(x0,x1,15); tf_round(x0,x1,26); tf_round(x0,x1,6);
    x0 += k1; x1 += k2 + 1u;
    tf_round(x0,x1,17); tf_round(x0,x1,29); tf_round(x0,x1,16); tf_round(x0,x1,24);
    x0 += k2; x1 += k0 + 2u;
    tf_round(x0,x1,13); tf_round(x0,x1,15); tf_round(x0,x1,26); tf_round(x0,x1,6);
    x0 += k0; x1 += k1 + 3u;
    tf_round(x0,x1,17); tf_round(x0,x1,29); tf_round(x0,x1,16); tf_round(x0,x1,24);
    x0 += k1; x1 += k2 + 4u;
    tf_round(x0,x1,13); tf_round(x0,x1,15); tf_round(x0,x1,26); tf_round(x0,x1,6);
    o0 = x0 + k2; o1 = x1 + k0 + 5u;
}

// ---------------- shared memory union (phases are time-separated) ----------
struct FusedSM {                    // phase D (per-wave rings, R5-proven)
    u64 rows[8][16][64];            // [wave][row&15][k*8+pl]        64 KB
    u64 wp[8][8][128];              // [wave][t&7][win 64 | post 64]  64 KB
    u64 potC[8][2][8][10];          // [wave][step][pl][k pad->80B]   10 KB
    u64 ltpC[8][2][8][10];          //                                10 KB
    uint32_t cntR[8][8][16];        // [wave][t&7][o-local]            4 KB
};
struct FwSM { uint32_t wl32[TT * 65]; int fwl[BB]; };   // phase B, 53 KB
struct __align__(16) CSM { u64 ring[6][3136]; };        // phase C: 6 x 25088B ring
union SMem { FusedSM f; FwSM w; CSM c; };

__device__ __forceinline__ void gridsync(uint32_t* c, uint32_t target) {
    __syncthreads();
    if (threadIdx.x == 0) {
        __threadfence();   // release stores (agent scope)
        __hip_atomic_fetch_add(c, 1u, __ATOMIC_ACQ_REL, __HIP_MEMORY_SCOPE_AGENT);
        while (__hip_atomic_load(c, __ATOMIC_ACQUIRE, __HIP_MEMORY_SCOPE_AGENT)
               < target)
            __builtin_amdgcn_s_sleep(8);
        __threadfence();
    }
    __syncthreads();
}

__global__ __launch_bounds__(512, 1) void k_mono(
        const int* __restrict__ x,
        const float* __restrict__ L0,
        const float* __restrict__ p0arr,
        uint32_t* __restrict__ syncc,
        uint8_t* __restrict__ widx,
        uint32_t* __restrict__ cntg,
        u64* __restrict__ winbits,
        u64* __restrict__ postbits,
        u64* __restrict__ bitB,
        float* __restrict__ outL,
        float* __restrict__ outp) {
    __shared__ SMem sm;
    __shared__ uint32_t smclaim;
    const int tid = threadIdx.x;
    const int bid = blockIdx.x;

    // ====== phase A: winners, spread over ALL 240 blocks (<=1 per thread) ==
    {
        int idx = bid * 214 + tid;       // 240*214 = 51360 >= 51200
        if (tid < 214 && idx < TT * BB) {
            int t = idx >> 8, b = idx & 255;
            uint32_t fk0, fk1;
            threefry(0u, 42u, 0u, (uint32_t)t, fk0, fk1);  // fold_in(key(42), t)
            uint32_t bestkey = 0u;
            int bo = 0;
            int nbase = b * OO;
            for (int o = 0; o < OO; ++o) {
                uint32_t n = (uint32_t)(nbase + o);
                uint32_t lo = (n < NHALF) ? n : n - NHALF;
                uint32_t v0, v1;
                threefry(fk0, fk1, lo, lo + NHALF, v0, v1);
                uint32_t bits = (n < NHALF) ? v0 : v1;
                uint32_t key = bits >> 9;   // monotone proxy for gumbel
                if (key > bestkey) { bestkey = key; bo = o; }
            }
            widx[idx] = (uint8_t)bo;
        }
    }
    gridsync(&syncc[0], (uint32_t)NBLK);

    // ====== phase B (blocks 0..99): fwpost; blocks >=100 go straight to C ==
    if (bid < 100) {
        const uint32_t* wsrc = (const uint32_t*)widx;
        for (int g = tid; g < TT * 64; g += 512)
            sm.w.wl32[(g >> 6) * 65 + (g & 63)] = wsrc[g];
        __syncthreads();
        int o = bid;
        if (tid < 64) {
            int f0 = 255, f1 = 255, f2 = 255, f3 = 255;
            for (int t = 0; t < TT; ++t) {
                uint32_t w4 = sm.w.wl32[t * 65 + tid];
                if (((w4      ) & 255u) == (uint32_t)o && f0 == 255) f0 = t;
                if (((w4 >>  8) & 255u) == (uint32_t)o && f1 == 255) f1 = t;
                if (((w4 >> 16) & 255u) == (uint32_t)o && f2 == 255) f2 = t;
                if (((w4 >> 24) & 255u) == (uint32_t)o && f3 == 255) f3 = t;
            }
            sm.w.fwl[4 * tid + 0] = f0; sm.w.fwl[4 * tid + 1] = f1;
            sm.w.fwl[4 * tid + 2] = f2; sm.w.fwl[4 * tid + 3] = f3;
        }
        __syncthreads();
        if (tid < TT) {
            int t = tid;
            u64 wbA[4], pbA[4];
            uint32_t c = 0;
            #pragma unroll
            for (int k = 0; k < 4; ++k) {
                u64 wacc = 0, pacc = 0;
                for (int q2 = 0; q2 < 16; ++q2) {
                    uint32_t w4 = sm.w.wl32[t * 65 + k * 16 + q2];
                    #pragma unroll
                    for (int j = 0; j < 4; ++j) {
                        int bl = q2 * 4 + j;
                        bool win = (((w4 >> (8 * j)) & 255u) == (uint32_t)o);
                        c += win ? 1u : 0u;
                        bool post = (sm.w.fwl[k * 64 + q2 * 4 + j] < t) && !win;
                        u64 bit = 1ull << bl;
                        if (win)  wacc |= bit;
                        if (post) pacc |= bit;
                    }
                }
                wbA[k] = wacc; pbA[k] = pacc;
            }
            size_t base = (size_t)(t * OO + o) * 4;
            #pragma unroll
            for (int k = 0; k < 4; ++k) {
                winbits[base + k] = wbA[k];
                postbits[base + k] = pbA[k];
            }
            cntg[t * OO + o] = c;
        }
        __syncthreads();
    }

    // ====== phase C: bit-pack via GLD16 LDS-ring streaming ================
    // 6-slot ring (25KB = one batch-slab of 4 timesteps each). Waves 0..5
    // own slot bl%6 and issue 25 GLD16 per slab (zero VGPR cost, 25KB/wave
    // in flight => ~150KB/block, ~30MB grid-wide >> 6MB latency-BW product).
    // Owner-only vmcnt(0); two raw s_barriers per slab; all 512 threads
    // consume from LDS via ds_read_b128 (16B stride = conflict-free).
    {
        const v4i* xp = (const v4i*)x;
        const int wv = tid >> 6, ll = tid & 63;
        const size_t slabstride = (size_t)TT * 392;   // v4i per batch slab
        for (;;) {
            __syncthreads();
            if (tid == 0)
                smclaim = __hip_atomic_fetch_add(&syncc[2], 1u, __ATOMIC_RELAXED,
                                                 __HIP_MEMORY_SCOPE_AGENT);
            __syncthreads();
            uint32_t u = smclaim;
            if (u >= 200u) break;
            int wb = u & 3, tc = u >> 2;
            size_t slab0 = ((size_t)(wb * 64) * TT + (size_t)tc * 4) * 392;
            u64 acc[4][4];
            #pragma unroll
            for (int q = 0; q < 4; ++q)
                #pragma unroll
                for (int c = 0; c < 4; ++c) acc[q][c] = 0;
            bool x4 = (tid < 32);          // 1568 = 3*512 + 32
            // prologue: waves 0..5 issue slabs 0..5
            if (wv < 6) {
                size_t sb = slab0 + (size_t)wv * slabstride;
                #pragma unroll
                for (int c = 0; c < 25; ++c) {
                    int e = c * 64 + ll;
                    if (e < 1568)
                        GLD16(xp + sb + e, (las_p)&sm.c.ring[wv][(size_t)e * 2]);
                }
            }
            for (int bl = 0; bl < 64; ++bl) {
                int slot = bl % 6;
                if (wv == slot)
                    asm volatile("s_waitcnt vmcnt(0)" ::: "memory");
                __builtin_amdgcn_s_barrier();
                __builtin_amdgcn_sched_barrier(0);
                u64 bit = 1ull << bl;
                const v4i* rb = (const v4i*)&sm.c.ring[slot][0];
                #pragma unroll
                for (int q = 0; q < 3; ++q) {
                    v4i v = rb[tid + q * 512];
                    if (v.x) acc[q][0] |= bit;
                    if (v.y) acc[q][1] |= bit;
                    if (v.z) acc[q][2] |= bit;
                    if (v.w) acc[q][3] |= bit;
                }
                if (x4) {
                    v4i v = rb[tid + 1536];
                    if (v.x) acc[3][0] |= bit;
                    if (v.y) acc[3][1] |= bit;
                    if (v.z) acc[3][2] |= bit;
                    if (v.w) acc[3][3] |= bit;
                }
                __builtin_amdgcn_sched_barrier(0);
                __builtin_amdgcn_s_barrier();       // slot fully consumed
                __builtin_amdgcn_sched_barrier(0);
                if (wv == slot && bl + 6 < 64) {    // refill freed slot
                    size_t sb = slab0 + (size_t)(bl + 6) * slabstride;
                    #pragma unroll
                    for (int c = 0; c < 25; ++c) {
                        int e = c * 64 + ll;
                        if (e < 1568)
                            GLD16(xp + sb + e,
                                  (las_p)&sm.c.ring[slot][(size_t)e * 2]);
                    }
                }
            }
            #pragma unroll
            for (int q = 0; q < 4; ++q) {
                if (q == 3 && !x4) continue;
                int p = tid + q * 512;
                int tp = (p >= 1176) ? 3 : (p >= 784) ? 2 : (p >= 392) ? 1 : 0;
                int iq = p - tp * 392;
                u64* dst = bitB + ((size_t)((tc * 4 + tp) * 4 + wb)) * INN + iq * 4;
                dst[0] = acc[q][0]; dst[1] = acc[q][1];
                dst[2] = acc[q][2]; dst[3] = acc[q][3];
            }
        }
    }
    gridsync(&syncc[1], (uint32_t)NBLK);

    // ====== phase D: wave-synchronous fused chains (R5 form, proven) ======
    {
        const int wv = tid >> 6, lane = tid & 63;
        int u = bid + NBLK * wv;
        if (u > UNITS) return;                      // idle waves
        if (u == UNITS) {                           // ---- prior chain ----
            int l = lane;
            bool has2 = (l + 64) < OO;
            float pa = p0arr[l];
            float pb = has2 ? p0arr[l + 64] : -1e30f;
            auto norm = [&]() {
                pa = fminf(fmaxf(pa, -5.0f), 0.0f);
                if (has2) pb = fminf(fmaxf(pb, -5.0f), 0.0f);
                float mx = has2 ? fmaxf(pa, pb) : pa;
                #pragma unroll
                for (int s = 32; s > 0; s >>= 1) mx = fmaxf(mx, __shfl_xor(mx, s, 64));
                float smv = expf(pa - mx) + (has2 ? expf(pb - mx) : 0.0f);
                #pragma unroll
                for (int s = 32; s > 0; s >>= 1) smv += __shfl_xor(smv, s, 64);
                float lse = logf(smv) + mx;
                pa -= lse;
                if (has2) pb -= lse;
            };
            norm();
            for (int t = 0; t < TT; ++t) {
                float eta = 0.001f / (float)(t + 1);
                float wma = (float)cntg[t * OO + l] * (1.0f / 256.0f);
                pa += eta * ((-5.0f * pa - 1.0f) * wma - (1.0f - wma));
                if (has2) {
                    float wmb = (float)cntg[t * OO + l + 64] * (1.0f / 256.0f);
                    pb += eta * ((-5.0f * pb - 1.0f) * wmb - (1.0f - wmb));
                }
                norm();
            }
            outp[l] = pa;
            if (has2) outp[l + 64] = pb;
            return;
        }

        const int pg = u % 98, og = u / 98;         // og 0..6
        const int p0 = pg * 8, o0 = og * 16;
        const int pl = lane & 7, ol = lane >> 3;    // 8 pl x 8 ol
        const int oA = o0 + ol, oB = oA + 8;
        const int i0 = p0 + pl, i1 = i0 + PAIRS;
        const bool actA = (oA < OO), actB = (oB < OO);

        // rows GLD: lane -> u64 pair (e0, e0+1), e = k*8+pl, 2 slots/GLD
        const int e0 = (lane & 31) * 2;
        const int wk0 = e0 >> 3, wpl0 = e0 & 7;
        const u64* rowg = bitB + (size_t)((wk0 & 3) * INN + (wk0 >> 2) * PAIRS
                                          + p0 + wpl0);
        // wp GLD: lanes<32 win, >=32 post; 1 slot (1KB) per GLD
        const int lw = lane & 31;
        const u64* wpg = (lane < 32) ? winbits : postbits;
        const bool wpact = (o0 + (lw >> 1)) < OO;
        const bool cntact = (lane < 8) && ((o0 + (lane & 3) * 4) < OO);

        auto issueG = [&](int G) {
            int r0 = 2 * G;
            {   // rows: slots r0&15, r0&15+1 (1 GLD, 64 lanes)
                int rr = r0 + (lane >> 5); if (rr > TT - 1) rr = TT - 1;
                GLD16(rowg + (size_t)rr * ROWSTRIDE,
                      (las_p)&sm.f.rows[wv][r0 & 15][0]);
            }
            {   // wp slot r0
                int rr = r0; if (rr > TT - 1) rr = TT - 1;
                if (wpact)
                    GLD16(wpg + ((size_t)rr * OO + o0) * 4 + 2 * lw,
                          (las_p)&sm.f.wp[wv][r0 & 7][0]);
            }
            {   // wp slot r0+1
                int rr = r0 + 1; if (rr > TT - 1) rr = TT - 1;
                if (wpact)
                    GLD16(wpg + ((size_t)rr * OO + o0) * 4 + 2 * lw,
                          (las_p)&sm.f.wp[wv][(r0 + 1) & 7][0]);
            }
            {   // cnt: 2 slots, 8 lanes
                if (cntact) {
                    int rr = r0 + (lane >> 2); if (rr > TT - 1) rr = TT - 1;
                    GLD16(cntg + (size_t)rr * OO + o0 + (lane & 3) * 4,
                          (las_p)&sm.f.cntR[wv][r0 & 7][0]);
                }
            }
        };

        // chain init (clamp + pairwise lse), proven first=1 path
        float aA = actA ? L0[(size_t)i0 * OO + oA] : -1.0f;
        float bA = actA ? L0[(size_t)i1 * OO + oA] : -1.0f;
        float aB = actB ? L0[(size_t)i0 * OO + oB] : -1.0f;
        float bB = actB ? L0[(size_t)i1 * OO + oB] : -1.0f;
        {
            aA = fminf(fmaxf(aA, -5.0f), 0.0f);
            bA = fminf(fmaxf(bA, -5.0f), 0.0f);
            float m = fmaxf(aA, bA), mn = fminf(aA, bA);
            float lse = __logf(1.0f + __expf(mn - m)) + m;
            aA -= lse; bA -= lse;
            aB = fminf(fmaxf(aB, -5.0f), 0.0f);
            bB = fminf(fmaxf(bB, -5.0f), 0.0f);
            float m2 = fmaxf(aB, bB), mn2 = fminf(aB, bB);
            float lse2 = __logf(1.0f + __expf(mn2 - m2)) + m2;
            aB -= lse2; bB -= lse2;
        }

        auto chainstep = [&](int t, int sp) {
            int s = t & 7;
            const u64* wpS = &sm.f.wp[wv][s][0];
            const u64* P = sm.f.potC[wv][sp][pl];
            const u64* Lt = sm.f.ltpC[wv][sp][pl];
            u64 P0 = P[0], P1 = P[1], P2 = P[2], P3 = P[3];
            u64 P4 = P[4], P5 = P[5], P6 = P[6], P7 = P[7];
            u64 Q0 = Lt[0], Q1 = Lt[1], Q2 = Lt[2], Q3 = Lt[3];
            u64 Q4 = Lt[4], Q5 = Lt[5], Q6 = Lt[6], Q7 = Lt[7];
            float eta = 0.001f / (float)(t + 1);
            // ---- chain A ----
            {
                u64 W0 = wpS[ol*4+0], W1 = wpS[ol*4+1], W2 = wpS[ol*4+2], W3 = wpS[ol*4+3];
                u64 S0 = wpS[64+ol*4+0], S1 = wpS[64+ol*4+1], S2 = wpS[64+ol*4+2], S3 = wpS[64+ol*4+3];
                float cw = (float)sm.f.cntR[wv][s][ol];
                float lt0 = (float)(__popcll(Q0&W0)+__popcll(Q1&W1)+__popcll(Q2&W2)+__popcll(Q3&W3));
                float lt1 = (float)(__popcll(Q4&W0)+__popcll(Q5&W1)+__popcll(Q6&W2)+__popcll(Q7&W3));
                float pp0 = (float)(__popcll(P0&S0)+__popcll(P1&S1)+__popcll(P2&S2)+__popcll(P3&S3));
                float pp1 = (float)(__popcll(P4&S0)+__popcll(P5&S1)+__popcll(P6&S2)+__popcll(P7&S3));
                float dw0 = (5.0f*__expf(-aA) - 1.0f)*(lt0*(1.0f/256.0f))
                          + (cw - lt0 - pp0)*(1.0f/256.0f);
                float dw1 = (5.0f*__expf(-bA) - 1.0f)*(lt1*(1.0f/256.0f))
                          + (cw - lt1 - pp1)*(1.0f/256.0f);
                aA += eta*dw0; bA += eta*dw1;
                aA = fminf(fmaxf(aA,-5.0f),0.0f);
                bA = fminf(fmaxf(bA,-5.0f),0.0f);
                float m = fmaxf(aA,bA), mn = fminf(aA,bA);
                float lse = __logf(1.0f + __expf(mn-m)) + m;
                aA -= lse; bA -= lse;
            }
            // ---- chain B ----
            {
                u64 W0 = wpS[(ol+8)*4+0], W1 = wpS[(ol+8)*4+1], W2 = wpS[(ol+8)*4+2], W3 = wpS[(ol+8)*4+3];
                u64 S0 = wpS[64+(ol+8)*4+0], S1 = wpS[64+(ol+8)*4+1], S2 = wpS[64+(ol+8)*4+2], S3 = wpS[64+(ol+8)*4+3];
                float cw = (float)sm.f.cntR[wv][s][ol+8];
                float lt0 = (float)(__popcll(Q0&W0)+__popcll(Q1&W1)+__popcll(Q2&W2)+__popcll(Q3&W3));
                float lt1 = (float)(__popcll(Q4&W0)+__popcll(Q5&W1)+__popcll(Q6&W2)+__popcll(Q7&W3));
                float pp0 = (float)(__popcll(P0&S0)+__popcll(P1&S1)+__popcll(P2&S2)+__popcll(P3&S3));
                float pp1 = (float)(__popcll(P4&S0)+__popcll(P5&S1)+__popcll(P6&S2)+__popcll(P7&S3));
                float dw0 = (5.0f*__expf(-aB) - 1.0f)*(lt0*(1.0f/256.0f))
                          + (cw - lt0 - pp0)*(1.0f/256.0f);
                float dw1 = (5.0f*__expf(-bB) - 1.0f)*(lt1*(1.0f/256.0f))
                          + (cw - lt1 - pp1)*(1.0f/256.0f);
                aB += eta*dw0; bB += eta*dw1;
                aB = fminf(fmaxf(aB,-5.0f),0.0f);
                bB = fminf(fmaxf(bB,-5.0f),0.0f);
                float m = fmaxf(aB,bB), mn = fminf(aB,bB);
                float lse = __logf(1.0f + __expf(mn-m)) + m;
                aB -= lse; bB -= lse;
            }
        };

        issueG(0);
        issueG(1);
        for (int I = 0; I < 100; ++I) {
            issueG(I + 2);
            asm volatile("s_waitcnt vmcnt(8)" ::: "memory");  // group I resident
            // window for steps 2I, 2I+1 (12 ring reads, OR-idempotent clamp)
            int b0 = 2 * I;
            u64 com = 0;
            #pragma unroll
            for (int j = 8; j >= 0; --j) {
                int r = b0 - j; r = (r < 0) ? 0 : r;
                com |= sm.f.rows[wv][r & 15][lane];
            }
            int r9 = b0 - 9;   r9 = (r9 < 0) ? 0 : r9;
            int r10 = b0 - 10; r10 = (r10 < 0) ? 0 : r10;
            u64 v9  = sm.f.rows[wv][r9 & 15][lane];
            u64 v10 = sm.f.rows[wv][r10 & 15][lane];
            u64 vt2 = sm.f.rows[wv][(b0 + 1) & 15][lane];
            u64 pot1 = com | v9;
            u64 pot2 = com | vt2;
            sm.f.potC[wv][0][lane & 7][lane >> 3] = pot1;
            sm.f.potC[wv][1][lane & 7][lane >> 3] = pot2;
            sm.f.ltpC[wv][0][lane & 7][lane >> 3] = pot1 | v10;
            sm.f.ltpC[wv][1][lane & 7][lane >> 3] = pot2 | v9;
            asm volatile("s_waitcnt lgkmcnt(0)" ::: "memory");  // cross-lane publish
            chainstep(b0, 0);
            chainstep(b0 + 1, 1);
        }
        if (actA) {
            outL[(size_t)i0 * OO + oA] = aA;
            outL[(size_t)i1 * OO + oA] = bA;
        }
        if (actB) {
            outL[(size_t)i0 * OO + oB] = aB;
            outL[(size_t)i1 * OO + oB] = bB;
        }
    }
}

extern "C" void kernel_launch(void* const* d_in, const int* in_sizes, int n_in,
                              void* d_out, int out_size, void* d_ws, size_t ws_size,
                              hipStream_t stream) {
    const int*   x  = (const int*)d_in[0];
    const float* L0 = (const float*)d_in[1];
    const float* p0 = (const float*)d_in[2];
    float* out = (float*)d_out;

    char* ws = (char*)d_ws;
    size_t off = 0;
    auto alloc = [&](size_t bytes) -> void* {
        off = (off + 255) & ~(size_t)255;
        void* p = ws + off;
        off += bytes;
        return p;
    };
    uint32_t* syncc    = (uint32_t*)alloc(256);      // [0],[1] sync; [2] C-queue
    uint8_t*  widx     = (uint8_t*) alloc((size_t)TT * BB);
    uint32_t* cntg     = (uint32_t*)alloc((size_t)TT * OO * 4);
    u64*      winbits  = (u64*)     alloc((size_t)TT * OO * 4 * 8);
    u64*      postbits = (u64*)     alloc((size_t)TT * OO * 4 * 8);
    u64*      bitB     = (u64*)     alloc((size_t)TT * 4 * INN * 8);
    (void)ws_size;

    hipMemsetAsync(syncc, 0, 256, stream);   // zero sync/queue counters
    hipLaunchKernelGGL(k_mono, dim3(NBLK), dim3(512), 0, stream,
                       x, L0, p0, syncc, widx, cntg, winbits, postbits, bitB,
                       out, out + (size_t)INN * OO);
}

// Round 8
// 648.265 us; speedup vs baseline: 1.1242x; 1.0575x over previous
//
#include <hip/hip_runtime.h>
#include <stdint.h>

#define BB 256      // batch
#define TT 200      // timesteps
#define INN 1568    // inputs
#define OO 100      // outputs
#define PAIRS 784   // INN/2
#define NHALF 12800 // (BB*OO)/2
#define ROWSTRIDE (4 * INN)
#define DW 4        // waves per k_chains block

typedef unsigned long long u64;
typedef __attribute__((ext_vector_type(4))) int v4i;

// async global->LDS (16 B/lane); dest = wave-uniform base + lane*16
typedef const __attribute__((address_space(1))) uint32_t* gas_p;
typedef __attribute__((address_space(3))) uint32_t* las_p;
#define GLD16(g, l) __builtin_amdgcn_global_load_lds((gas_p)(g), (las_p)(l), 16, 0, 0)

// ---------------- threefry2x32 (JAX-compatible) ----------------
__device__ __forceinline__ void tf_round(uint32_t& x0, uint32_t& x1, int r) {
    x0 += x1;
    x1 = (x1 << r) | (x1 >> (32 - r));
    x1 ^= x0;
}

__device__ __forceinline__ void threefry(uint32_t k0, uint32_t k1,
                                         uint32_t x0, uint32_t x1,
                                         uint32_t& o0, uint32_t& o1) {
    uint32_t k2 = k0 ^ k1 ^ 0x1BD11BDAu;
    x0 += k0; x1 += k1;
    tf_round(x0,x1,13); tf_round(x0,x1,15); tf_round(x0,x1,26); tf_round(x0,x1,6);
    x0 += k1; x1 += k2 + 1u;
    tf_round(x0,x1,17); tf_round(x0,x1,29); tf_round(x0,x1,16); tf_round(x0,x1,24);
    x0 += k2; x1 += k0 + 2u;
    tf_round(x0,x1,13); tf_round(x0,x1,15); tf_round(x0,x1,26); tf_round(x0,x1,6);
    x0 += k0; x1 += k1 + 3u;
    tf_round(x0,x1,17); tf_round(x0,x1,29); tf_round(x0,x1,16); tf_round(x0,x1,24);
    x0 += k1; x1 += k2 + 4u;
    tf_round(x0,x1,13); tf_round(x0,x1,15); tf_round(x0,x1,26); tf_round(x0,x1,6);
    o0 = x0 + k2; o1 = x1 + k0 + 5u;
}

// ===== K1: winners (A) — 100 blocks x 512, ~8 µs ==========================
__global__ __launch_bounds__(512) void k_win(uint8_t* __restrict__ widx) {
    int idx = blockIdx.x * 512 + threadIdx.x;   // 100*512 = TT*BB exactly
    int t = idx >> 8, b = idx & 255;
    uint32_t fk0, fk1;
    threefry(0u, 42u, 0u, (uint32_t)t, fk0, fk1);   // fold_in(key(42), t)
    uint32_t bestkey = 0u;
    int bo = 0;
    int nbase = b * OO;
    for (int o = 0; o < OO; ++o) {
        uint32_t n = (uint32_t)(nbase + o);
        uint32_t lo = (n < NHALF) ? n : n - NHALF;
        uint32_t v0, v1;
        threefry(fk0, fk1, lo, lo + NHALF, v0, v1);
        uint32_t bits = (n < NHALF) ? v0 : v1;
        uint32_t key = bits >> 9;       // monotone proxy for gumbel
        if (key > bestkey) { bestkey = key; bo = o; }
    }
    widx[idx] = (uint8_t)bo;
}

// ===== K2: fwpost (B) — proven 13 µs ======================================
__global__ __launch_bounds__(256) void k_fwpost(const uint8_t* __restrict__ widx,
                                                u64* __restrict__ winbits,
                                                u64* __restrict__ postbits,
                                                uint32_t* __restrict__ cnt) {
    __shared__ uint32_t wl32[TT * 65];
    __shared__ int fwl[BB];
    int o = blockIdx.x;
    int tid = threadIdx.x;
    const uint32_t* wsrc = (const uint32_t*)widx;
    for (int g = tid; g < TT * 64; g += 256) {
        int t = g >> 6, w = g & 63;
        wl32[t * 65 + w] = wsrc[g];
    }
    __syncthreads();
    if (tid < 64) {
        int f0 = 255, f1 = 255, f2 = 255, f3 = 255;
        for (int t = 0; t < TT; ++t) {
            uint32_t w4 = wl32[t * 65 + tid];
            if (((w4      ) & 255u) == (uint32_t)o && f0 == 255) f0 = t;
            if (((w4 >>  8) & 255u) == (uint32_t)o && f1 == 255) f1 = t;
            if (((w4 >> 16) & 255u) == (uint32_t)o && f2 == 255) f2 = t;
            if (((w4 >> 24) & 255u) == (uint32_t)o && f3 == 255) f3 = t;
        }
        fwl[4 * tid + 0] = f0; fwl[4 * tid + 1] = f1;
        fwl[4 * tid + 2] = f2; fwl[4 * tid + 3] = f3;
    }
    __syncthreads();
    if (tid < TT) {
        int t = tid;
        u64 wbA[4], pbA[4];
        uint32_t c = 0;
        #pragma unroll
        for (int k = 0; k < 4; ++k) {
            u64 wacc = 0, pacc = 0;
            for (int q2 = 0; q2 < 16; ++q2) {
                uint32_t w4 = wl32[t * 65 + k * 16 + q2];
                #pragma unroll
                for (int j = 0; j < 4; ++j) {
                    int bl = q2 * 4 + j;
                    bool win = (((w4 >> (8 * j)) & 255u) == (uint32_t)o);
                    c += win ? 1u : 0u;
                    bool post = (fwl[k * 64 + q2 * 4 + j] < t) && !win;
                    u64 bit = 1ull << bl;
                    if (win)  wacc |= bit;
                    if (post) pacc |= bit;
                }
            }
            wbA[k] = wacc; pbA[k] = pacc;
        }
        size_t base = (size_t)(t * OO + o) * 4;
        #pragma unroll
        for (int k = 0; k < 4; ++k) {
            winbits[base + k] = wbA[k];
            postbits[base + k] = pbA[k];
        }
        cnt[t * OO + o] = c;
    }
}

// ===== K3: x bit-pack (C) — GLD16 LDS-ring, 200 blocks, static unit ======
__global__ __launch_bounds__(512) void k_pack(const int* __restrict__ x,
                                              u64* __restrict__ bitB) {
    __shared__ __align__(16) u64 ring[6][3136];   // 6 x 25 KB slabs
    const v4i* xp = (const v4i*)x;
    const int tid = threadIdx.x;
    const int wv = tid >> 6, ll = tid & 63;
    const size_t slabstride = (size_t)TT * 392;   // v4i per batch slab
    int u = blockIdx.x;                           // 0..199
    int wb = u & 3, tc = u >> 2;
    size_t slab0 = ((size_t)(wb * 64) * TT + (size_t)tc * 4) * 392;
    u64 acc[4][4];
    #pragma unroll
    for (int q = 0; q < 4; ++q)
        #pragma unroll
        for (int c = 0; c < 4; ++c) acc[q][c] = 0;
    bool x4 = (tid < 32);          // 1568 = 3*512 + 32
    if (wv < 6) {                  // prologue: slabs 0..5
        size_t sb = slab0 + (size_t)wv * slabstride;
        #pragma unroll
        for (int c = 0; c < 25; ++c) {
            int e = c * 64 + ll;
            if (e < 1568)
                GLD16(xp + sb + e, (las_p)&ring[wv][(size_t)e * 2]);
        }
    }
    for (int bl = 0; bl < 64; ++bl) {
        int slot = bl % 6;
        if (wv == slot)
            asm volatile("s_waitcnt vmcnt(0)" ::: "memory");
        __builtin_amdgcn_s_barrier();
        __builtin_amdgcn_sched_barrier(0);
        u64 bit = 1ull << bl;
        const v4i* rb = (const v4i*)&ring[slot][0];
        #pragma unroll
        for (int q = 0; q < 3; ++q) {
            v4i v = rb[tid + q * 512];
            if (v.x) acc[q][0] |= bit;
            if (v.y) acc[q][1] |= bit;
            if (v.z) acc[q][2] |= bit;
            if (v.w) acc[q][3] |= bit;
        }
        if (x4) {
            v4i v = rb[tid + 1536];
            if (v.x) acc[3][0] |= bit;
            if (v.y) acc[3][1] |= bit;
            if (v.z) acc[3][2] |= bit;
            if (v.w) acc[3][3] |= bit;
        }
        __builtin_amdgcn_sched_barrier(0);
        __builtin_amdgcn_s_barrier();       // slot fully consumed
        __builtin_amdgcn_sched_barrier(0);
        if (wv == slot && bl + 6 < 64) {    // refill freed slot
            size_t sb = slab0 + (size_t)(bl + 6) * slabstride;
            #pragma unroll
            for (int c = 0; c < 25; ++c) {
                int e = c * 64 + ll;
                if (e < 1568)
                    GLD16(xp + sb + e, (las_p)&ring[slot][(size_t)e * 2]);
            }
        }
    }
    #pragma unroll
    for (int q = 0; q < 4; ++q) {
        if (q == 3 && !x4) continue;
        int p = tid + q * 512;
        int tp = (p >= 1176) ? 3 : (p >= 784) ? 2 : (p >= 392) ? 1 : 0;
        int iq = p - tp * 392;
        u64* dst = bitB + ((size_t)((tc * 4 + tp) * 4 + wb)) * INN + iq * 4;
        dst[0] = acc[q][0]; dst[1] = acc[q][1];
        dst[2] = acc[q][2]; dst[3] = acc[q][3];
    }
}

// ===== K4: chains (D) — R5 wave-sync form, 172 blocks x 4 waves ==========
struct ChSM {
    u64 rows[DW][16][64];           // [wave][row&15][k*8+pl]     32 KB
    u64 wp[DW][8][128];             // [wave][t&7][win64|post64]  32 KB
    u64 potC[DW][2][8][10];         // [wave][step][pl][k]         5 KB
    u64 ltpC[DW][2][8][10];         //                             5 KB
    uint32_t cntR[DW][8][16];       //                             2 KB
};                                  // total ~77 KB -> 2 blocks/CU

__global__ __launch_bounds__(256) void k_chains(
        const float* __restrict__ L0,
        const float* __restrict__ p0arr,
        const u64* __restrict__ bitB,
        const u64* __restrict__ winbits,
        const u64* __restrict__ postbits,
        const uint32_t* __restrict__ cntg,
        float* __restrict__ outL,
        float* __restrict__ outp) {
    __shared__ ChSM sm;
    const int tid = threadIdx.x;
    const int wv = tid >> 6, lane = tid & 63;
    int u = blockIdx.x * DW + wv;               // 172*4 = 688 waves
    if (u > 686) return;
    if (u == 686) {                             // ---- prior chain ----
        int l = lane;
        bool has2 = (l + 64) < OO;
        float pa = p0arr[l];
        float pb = has2 ? p0arr[l + 64] : -1e30f;
        auto norm = [&]() {
            pa = fminf(fmaxf(pa, -5.0f), 0.0f);
            if (has2) pb = fminf(fmaxf(pb, -5.0f), 0.0f);
            float mx = has2 ? fmaxf(pa, pb) : pa;
            #pragma unroll
            for (int s = 32; s > 0; s >>= 1) mx = fmaxf(mx, __shfl_xor(mx, s, 64));
            float smv = expf(pa - mx) + (has2 ? expf(pb - mx) : 0.0f);
            #pragma unroll
            for (int s = 32; s > 0; s >>= 1) smv += __shfl_xor(smv, s, 64);
            float lse = logf(smv) + mx;
            pa -= lse;
            if (has2) pb -= lse;
        };
        norm();
        for (int t = 0; t < TT; ++t) {
            float eta = 0.001f / (float)(t + 1);
            float wma = (float)cntg[t * OO + l] * (1.0f / 256.0f);
            pa += eta * ((-5.0f * pa - 1.0f) * wma - (1.0f - wma));
            if (has2) {
                float wmb = (float)cntg[t * OO + l + 64] * (1.0f / 256.0f);
                pb += eta * ((-5.0f * pb - 1.0f) * wmb - (1.0f - wmb));
            }
            norm();
        }
        outp[l] = pa;
        if (has2) outp[l + 64] = pb;
        return;
    }

    const int pg = u % 98, og = u / 98;         // og 0..6
    const int p0 = pg * 8, o0 = og * 16;
    const int pl = lane & 7, ol = lane >> 3;    // 8 pl x 8 ol
    const int oA = o0 + ol, oB = oA + 8;
    const int i0 = p0 + pl, i1 = i0 + PAIRS;
    const bool actA = (oA < OO), actB = (oB < OO);

    // rows GLD: lane -> u64 pair (e0, e0+1), e = k*8+pl; 1 GLD fills 2 slots
    const int e0 = (lane & 31) * 2;
    const int wk0 = e0 >> 3, wpl0 = e0 & 7;
    const u64* rowg = bitB + (size_t)((wk0 & 3) * INN + (wk0 >> 2) * PAIRS
                                      + p0 + wpl0);
    const int lw = lane & 31;
    const u64* wpg = (lane < 32) ? winbits : postbits;
    const bool wpact = (o0 + (lw >> 1)) < OO;
    const bool cntact = (lane < 8) && ((o0 + (lane & 3) * 4) < OO);

    auto issueG = [&](int G) {
        int r0 = 2 * G;
        {   // rows: slots r0&15, (r0&15)+1 (1 GLD, 64 lanes)
            int rr = r0 + (lane >> 5); if (rr > TT - 1) rr = TT - 1;
            GLD16(rowg + (size_t)rr * ROWSTRIDE,
                  (las_p)&sm.rows[wv][r0 & 15][0]);
        }
        {   // wp slot r0
            int rr = r0; if (rr > TT - 1) rr = TT - 1;
            if (wpact)
                GLD16(wpg + ((size_t)rr * OO + o0) * 4 + 2 * lw,
                      (las_p)&sm.wp[wv][r0 & 7][0]);
        }
        {   // wp slot r0+1
            int rr = r0 + 1; if (rr > TT - 1) rr = TT - 1;
            if (wpact)
                GLD16(wpg + ((size_t)rr * OO + o0) * 4 + 2 * lw,
                      (las_p)&sm.wp[wv][(r0 + 1) & 7][0]);
        }
        {   // cnt: 2 slots, 8 lanes
            if (cntact) {
                int rr = r0 + (lane >> 2); if (rr > TT - 1) rr = TT - 1;
                GLD16(cntg + (size_t)rr * OO + o0 + (lane & 3) * 4,
                      (las_p)&sm.cntR[wv][r0 & 7][0]);
            }
        }
    };

    // chain init (clamp + pairwise lse)
    float aA = actA ? L0[(size_t)i0 * OO + oA] : -1.0f;
    float bA = actA ? L0[(size_t)i1 * OO + oA] : -1.0f;
    float aB = actB ? L0[(size_t)i0 * OO + oB] : -1.0f;
    float bB = actB ? L0[(size_t)i1 * OO + oB] : -1.0f;
    {
        aA = fminf(fmaxf(aA, -5.0f), 0.0f);
        bA = fminf(fmaxf(bA, -5.0f), 0.0f);
        float m = fmaxf(aA, bA), mn = fminf(aA, bA);
        float lse = __logf(1.0f + __expf(mn - m)) + m;
        aA -= lse; bA -= lse;
        aB = fminf(fmaxf(aB, -5.0f), 0.0f);
        bB = fminf(fmaxf(bB, -5.0f), 0.0f);
        float m2 = fmaxf(aB, bB), mn2 = fminf(aB, bB);
        float lse2 = __logf(1.0f + __expf(mn2 - m2)) + m2;
        aB -= lse2; bB -= lse2;
    }

    auto chainstep = [&](int t, int sp) {
        int s = t & 7;
        const u64* wpS = &sm.wp[wv][s][0];
        const u64* P = sm.potC[wv][sp][pl];
        const u64* Lt = sm.ltpC[wv][sp][pl];
        u64 P0 = P[0], P1 = P[1], P2 = P[2], P3 = P[3];
        u64 P4 = P[4], P5 = P[5], P6 = P[6], P7 = P[7];
        u64 Q0 = Lt[0], Q1 = Lt[1], Q2 = Lt[2], Q3 = Lt[3];
        u64 Q4 = Lt[4], Q5 = Lt[5], Q6 = Lt[6], Q7 = Lt[7];
        float eta = 0.001f / (float)(t + 1);
        {
            u64 W0 = wpS[ol*4+0], W1 = wpS[ol*4+1], W2 = wpS[ol*4+2], W3 = wpS[ol*4+3];
            u64 S0 = wpS[64+ol*4+0], S1 = wpS[64+ol*4+1], S2 = wpS[64+ol*4+2], S3 = wpS[64+ol*4+3];
            float cw = (float)sm.cntR[wv][s][ol];
            float lt0 = (float)(__popcll(Q0&W0)+__popcll(Q1&W1)+__popcll(Q2&W2)+__popcll(Q3&W3));
            float lt1 = (float)(__popcll(Q4&W0)+__popcll(Q5&W1)+__popcll(Q6&W2)+__popcll(Q7&W3));
            float pp0 = (float)(__popcll(P0&S0)+__popcll(P1&S1)+__popcll(P2&S2)+__popcll(P3&S3));
            float pp1 = (float)(__popcll(P4&S0)+__popcll(P5&S1)+__popcll(P6&S2)+__popcll(P7&S3));
            float dw0 = (5.0f*__expf(-aA) - 1.0f)*(lt0*(1.0f/256.0f))
                      + (cw - lt0 - pp0)*(1.0f/256.0f);
            float dw1 = (5.0f*__expf(-bA) - 1.0f)*(lt1*(1.0f/256.0f))
                      + (cw - lt1 - pp1)*(1.0f/256.0f);
            aA += eta*dw0; bA += eta*dw1;
            aA = fminf(fmaxf(aA,-5.0f),0.0f);
            bA = fminf(fmaxf(bA,-5.0f),0.0f);
            float m = fmaxf(aA,bA), mn = fminf(aA,bA);
            float lse = __logf(1.0f + __expf(mn-m)) + m;
            aA -= lse; bA -= lse;
        }
        {
            u64 W0 = wpS[(ol+8)*4+0], W1 = wpS[(ol+8)*4+1], W2 = wpS[(ol+8)*4+2], W3 = wpS[(ol+8)*4+3];
            u64 S0 = wpS[64+(ol+8)*4+0], S1 = wpS[64+(ol+8)*4+1], S2 = wpS[64+(ol+8)*4+2], S3 = wpS[64+(ol+8)*4+3];
            float cw = (float)sm.cntR[wv][s][ol+8];
            float lt0 = (float)(__popcll(Q0&W0)+__popcll(Q1&W1)+__popcll(Q2&W2)+__popcll(Q3&W3));
            float lt1 = (float)(__popcll(Q4&W0)+__popcll(Q5&W1)+__popcll(Q6&W2)+__popcll(Q7&W3));
            float pp0 = (float)(__popcll(P0&S0)+__popcll(P1&S1)+__popcll(P2&S2)+__popcll(P3&S3));
            float pp1 = (float)(__popcll(P4&S0)+__popcll(P5&S1)+__popcll(P6&S2)+__popcll(P7&S3));
            float dw0 = (5.0f*__expf(-aB) - 1.0f)*(lt0*(1.0f/256.0f))
                      + (cw - lt0 - pp0)*(1.0f/256.0f);
            float dw1 = (5.0f*__expf(-bB) - 1.0f)*(lt1*(1.0f/256.0f))
                      + (cw - lt1 - pp1)*(1.0f/256.0f);
            aB += eta*dw0; bB += eta*dw1;
            aB = fminf(fmaxf(aB,-5.0f),0.0f);
            bB = fminf(fmaxf(bB,-5.0f),0.0f);
            float m = fmaxf(aB,bB), mn = fminf(aB,bB);
            float lse = __logf(1.0f + __expf(mn-m)) + m;
            aB -= lse; bB -= lse;
        }
    };

    issueG(0);
    issueG(1);
    for (int I = 0; I < 100; ++I) {
        issueG(I + 2);
        asm volatile("s_waitcnt vmcnt(8)" ::: "memory");  // group I resident
        int b0 = 2 * I;
        u64 com = 0;
        #pragma unroll
        for (int j = 8; j >= 0; --j) {
            int r = b0 - j; r = (r < 0) ? 0 : r;
            com |= sm.rows[wv][r & 15][lane];
        }
        int r9 = b0 - 9;   r9 = (r9 < 0) ? 0 : r9;
        int r10 = b0 - 10; r10 = (r10 < 0) ? 0 : r10;
        u64 v9  = sm.rows[wv][r9 & 15][lane];
        u64 v10 = sm.rows[wv][r10 & 15][lane];
        u64 vt2 = sm.rows[wv][(b0 + 1) & 15][lane];
        u64 pot1 = com | v9;
        u64 pot2 = com | vt2;
        sm.potC[wv][0][lane & 7][lane >> 3] = pot1;
        sm.potC[wv][1][lane & 7][lane >> 3] = pot2;
        sm.ltpC[wv][0][lane & 7][lane >> 3] = pot1 | v10;
        sm.ltpC[wv][1][lane & 7][lane >> 3] = pot2 | v9;
        asm volatile("s_waitcnt lgkmcnt(0)" ::: "memory");  // cross-lane publish
        chainstep(b0, 0);
        chainstep(b0 + 1, 1);
    }
    if (actA) {
        outL[(size_t)i0 * OO + oA] = aA;
        outL[(size_t)i1 * OO + oA] = bA;
    }
    if (actB) {
        outL[(size_t)i0 * OO + oB] = aB;
        outL[(size_t)i1 * OO + oB] = bB;
    }
}

extern "C" void kernel_launch(void* const* d_in, const int* in_sizes, int n_in,
                              void* d_out, int out_size, void* d_ws, size_t ws_size,
                              hipStream_t stream) {
    const int*   x  = (const int*)d_in[0];
    const float* L0 = (const float*)d_in[1];
    const float* p0 = (const float*)d_in[2];
    float* out = (float*)d_out;

    char* ws = (char*)d_ws;
    size_t off = 0;
    auto alloc = [&](size_t bytes) -> void* {
        off = (off + 255) & ~(size_t)255;
        void* p = ws + off;
        off += bytes;
        return p;
    };
    uint8_t*  widx     = (uint8_t*) alloc((size_t)TT * BB);
    uint32_t* cntg     = (uint32_t*)alloc((size_t)TT * OO * 4);
    u64*      winbits  = (u64*)     alloc((size_t)TT * OO * 4 * 8);
    u64*      postbits = (u64*)     alloc((size_t)TT * OO * 4 * 8);
    u64*      bitB     = (u64*)     alloc((size_t)TT * 4 * INN * 8);
    (void)ws_size;

    hipLaunchKernelGGL(k_win,    dim3(100), dim3(512), 0, stream, widx);
    hipLaunchKernelGGL(k_fwpost, dim3(100), dim3(256), 0, stream,
                       widx, winbits, postbits, cntg);
    hipLaunchKernelGGL(k_pack,   dim3(200), dim3(512), 0, stream, x, bitB);
    hipLaunchKernelGGL(k_chains, dim3(172), dim3(256), 0, stream,
                       L0, p0, bitB, winbits, postbits, cntg,
                       out, out + (size_t)INN * OO);
}

// Round 9
// 619.224 us; speedup vs baseline: 1.1770x; 1.0469x over previous
//
#include <hip/hip_runtime.h>
#include <stdint.h>

#define BB 256      // batch
#define TT 200      // timesteps
#define INN 1568    // inputs
#define OO 100      // outputs
#define PAIRS 784   // INN/2
#define NHALF 12800 // (BB*OO)/2
#define ROWSTRIDE (4 * INN)
#define DW 4        // waves per k_chains block

typedef unsigned long long u64;
typedef __attribute__((ext_vector_type(4))) int v4i;

// async global->LDS (16 B/lane); dest = wave-uniform base + lane*16
typedef const __attribute__((address_space(1))) uint32_t* gas_p;
typedef __attribute__((address_space(3))) uint32_t* las_p;
#define GLD16(g, l) __builtin_amdgcn_global_load_lds((gas_p)(g), (las_p)(l), 16, 0, 0)

// ---------------- threefry2x32 (JAX-compatible) ----------------
__device__ __forceinline__ void tf_round(uint32_t& x0, uint32_t& x1, int r) {
    x0 += x1;
    x1 = (x1 << r) | (x1 >> (32 - r));
    x1 ^= x0;
}

__device__ __forceinline__ void threefry(uint32_t k0, uint32_t k1,
                                         uint32_t x0, uint32_t x1,
                                         uint32_t& o0, uint32_t& o1) {
    uint32_t k2 = k0 ^ k1 ^ 0x1BD11BDAu;
    x0 += k0; x1 += k1;
    tf_round(x0,x1,13); tf_round(x0,x1,15); tf_round(x0,x1,26); tf_round(x0,x1,6);
    x0 += k1; x1 += k2 + 1u;
    tf_round(x0,x1,17); tf_round(x0,x1,29); tf_round(x0,x1,16); tf_round(x0,x1,24);
    x0 += k2; x1 += k0 + 2u;
    tf_round(x0,x1,13); tf_round(x0,x1,15); tf_round(x0,x1,26); tf_round(x0,x1,6);
    x0 += k0; x1 += k1 + 3u;
    tf_round(x0,x1,17); tf_round(x0,x1,29); tf_round(x0,x1,16); tf_round(x0,x1,24);
    x0 += k1; x1 += k2 + 4u;
    tf_round(x0,x1,13); tf_round(x0,x1,15); tf_round(x0,x1,26); tf_round(x0,x1,6);
    o0 = x0 + k2; o1 = x1 + k0 + 5u;
}

// ===== K1: pack (blocks 0..199) ∥ winners (blocks 200..299) ===============
// The two halves are data-independent; merging deletes one dispatch and
// hides win's ~8 µs of pure-VALU work inside pack's runtime.
__global__ __launch_bounds__(512) void k_packwin(const int* __restrict__ x,
                                                 u64* __restrict__ bitB,
                                                 uint8_t* __restrict__ widx) {
    const int tid = threadIdx.x;
    if (blockIdx.x >= 200) {            // ---- winners ----
        int idx = (blockIdx.x - 200) * 512 + tid;   // 100*512 = TT*BB
        int t = idx >> 8, b = idx & 255;
        uint32_t fk0, fk1;
        threefry(0u, 42u, 0u, (uint32_t)t, fk0, fk1);   // fold_in(key(42), t)
        uint32_t bestkey = 0u;
        int bo = 0;
        int nbase = b * OO;
        for (int o = 0; o < OO; ++o) {
            uint32_t n = (uint32_t)(nbase + o);
            uint32_t lo = (n < NHALF) ? n : n - NHALF;
            uint32_t v0, v1;
            threefry(fk0, fk1, lo, lo + NHALF, v0, v1);
            uint32_t bits = (n < NHALF) ? v0 : v1;
            uint32_t key = bits >> 9;       // monotone proxy for gumbel
            if (key > bestkey) { bestkey = key; bo = o; }
        }
        widx[idx] = (uint8_t)bo;
        return;
    }
    // ---- pack: GLD16 LDS-ring (R8-proven form) ----
    __shared__ __align__(16) u64 ring[6][3136];   // 6 x 25 KB slabs
    const v4i* xp = (const v4i*)x;
    const int wv = tid >> 6, ll = tid & 63;
    const size_t slabstride = (size_t)TT * 392;   // v4i per batch slab
    int u = blockIdx.x;                           // 0..199
    int wb = u & 3, tc = u >> 2;
    size_t slab0 = ((size_t)(wb * 64) * TT + (size_t)tc * 4) * 392;
    u64 acc[4][4];
    #pragma unroll
    for (int q = 0; q < 4; ++q)
        #pragma unroll
        for (int c = 0; c < 4; ++c) acc[q][c] = 0;
    bool x4 = (tid < 32);          // 1568 = 3*512 + 32
    if (wv < 6) {                  // prologue: slabs 0..5
        size_t sb = slab0 + (size_t)wv * slabstride;
        #pragma unroll
        for (int c = 0; c < 25; ++c) {
            int e = c * 64 + ll;
            if (e < 1568)
                GLD16(xp + sb + e, (las_p)&ring[wv][(size_t)e * 2]);
        }
    }
    for (int bl = 0; bl < 64; ++bl) {
        int slot = bl % 6;
        if (wv == slot)
            asm volatile("s_waitcnt vmcnt(0)" ::: "memory");
        __builtin_amdgcn_s_barrier();
        __builtin_amdgcn_sched_barrier(0);
        u64 bit = 1ull << bl;
        const v4i* rb = (const v4i*)&ring[slot][0];
        #pragma unroll
        for (int q = 0; q < 3; ++q) {
            v4i v = rb[tid + q * 512];
            if (v.x) acc[q][0] |= bit;
            if (v.y) acc[q][1] |= bit;
            if (v.z) acc[q][2] |= bit;
            if (v.w) acc[q][3] |= bit;
        }
        if (x4) {
            v4i v = rb[tid + 1536];
            if (v.x) acc[3][0] |= bit;
            if (v.y) acc[3][1] |= bit;
            if (v.z) acc[3][2] |= bit;
            if (v.w) acc[3][3] |= bit;
        }
        __builtin_amdgcn_sched_barrier(0);
        __builtin_amdgcn_s_barrier();       // slot fully consumed
        __builtin_amdgcn_sched_barrier(0);
        if (wv == slot && bl + 6 < 64) {    // refill freed slot
            size_t sb = slab0 + (size_t)(bl + 6) * slabstride;
            #pragma unroll
            for (int c = 0; c < 25; ++c) {
                int e = c * 64 + ll;
                if (e < 1568)
                    GLD16(xp + sb + e, (las_p)&ring[slot][(size_t)e * 2]);
            }
        }
    }
    #pragma unroll
    for (int q = 0; q < 4; ++q) {
        if (q == 3 && !x4) continue;
        int p = tid + q * 512;
        int tp = (p >= 1176) ? 3 : (p >= 784) ? 2 : (p >= 392) ? 1 : 0;
        int iq = p - tp * 392;
        u64* dst = bitB + ((size_t)((tc * 4 + tp) * 4 + wb)) * INN + iq * 4;
        dst[0] = acc[q][0]; dst[1] = acc[q][1];
        dst[2] = acc[q][2]; dst[3] = acc[q][3];
    }
}

// ===== K2: fwpost (B) — proven 13 µs ======================================
__global__ __launch_bounds__(256) void k_fwpost(const uint8_t* __restrict__ widx,
                                                u64* __restrict__ winbits,
                                                u64* __restrict__ postbits,
                                                uint32_t* __restrict__ cnt) {
    __shared__ uint32_t wl32[TT * 65];
    __shared__ int fwl[BB];
    int o = blockIdx.x;
    int tid = threadIdx.x;
    const uint32_t* wsrc = (const uint32_t*)widx;
    for (int g = tid; g < TT * 64; g += 256) {
        int t = g >> 6, w = g & 63;
        wl32[t * 65 + w] = wsrc[g];
    }
    __syncthreads();
    if (tid < 64) {
        int f0 = 255, f1 = 255, f2 = 255, f3 = 255;
        for (int t = 0; t < TT; ++t) {
            uint32_t w4 = wl32[t * 65 + tid];
            if (((w4      ) & 255u) == (uint32_t)o && f0 == 255) f0 = t;
            if (((w4 >>  8) & 255u) == (uint32_t)o && f1 == 255) f1 = t;
            if (((w4 >> 16) & 255u) == (uint32_t)o && f2 == 255) f2 = t;
            if (((w4 >> 24) & 255u) == (uint32_t)o && f3 == 255) f3 = t;
        }
        fwl[4 * tid + 0] = f0; fwl[4 * tid + 1] = f1;
        fwl[4 * tid + 2] = f2; fwl[4 * tid + 3] = f3;
    }
    __syncthreads();
    if (tid < TT) {
        int t = tid;
        u64 wbA[4], pbA[4];
        uint32_t c = 0;
        #pragma unroll
        for (int k = 0; k < 4; ++k) {
            u64 wacc = 0, pacc = 0;
            for (int q2 = 0; q2 < 16; ++q2) {
                uint32_t w4 = wl32[t * 65 + k * 16 + q2];
                #pragma unroll
                for (int j = 0; j < 4; ++j) {
                    int bl = q2 * 4 + j;
                    bool win = (((w4 >> (8 * j)) & 255u) == (uint32_t)o);
                    c += win ? 1u : 0u;
                    bool post = (fwl[k * 64 + q2 * 4 + j] < t) && !win;
                    u64 bit = 1ull << bl;
                    if (win)  wacc |= bit;
                    if (post) pacc |= bit;
                }
            }
            wbA[k] = wacc; pbA[k] = pacc;
        }
        size_t base = (size_t)(t * OO + o) * 4;
        #pragma unroll
        for (int k = 0; k < 4; ++k) {
            winbits[base + k] = wbA[k];
            postbits[base + k] = pbA[k];
        }
        cnt[t * OO + o] = c;
    }
}

// ===== K3: chains (D) — wave-sync, 4-group-deep prefetch ==================
// R8's 2-group pipeline exposed (latency - 2*iter) every iteration at 1-2
// waves/SIMD. Rings doubled (rows 32, wp/cnt 16); issueG(I+4); counted
// vmcnt(16) = 4 groups x 4 GLD16 in flight => ~1800cyc window >= HBM 900.
struct ChSM {
    u64 rows[DW][32][64];           // [wave][t&31][k*8+pl]      64 KB
    u64 wp[DW][16][128];            // [wave][t&15][win64|post64] 64 KB
    u64 potC[DW][2][8][10];         // [wave][step][pl][k]         5 KB
    u64 ltpC[DW][2][8][10];         //                             5 KB
    uint32_t cntR[DW][16][16];      // [wave][t&15][o-local]       4 KB
};                                  // 142 KB -> 1 block/CU, 172 blocks

__global__ __launch_bounds__(256, 1) void k_chains(
        const float* __restrict__ L0,
        const float* __restrict__ p0arr,
        const u64* __restrict__ bitB,
        const u64* __restrict__ winbits,
        const u64* __restrict__ postbits,
        const uint32_t* __restrict__ cntg,
        float* __restrict__ outL,
        float* __restrict__ outp) {
    __shared__ ChSM sm;
    const int tid = threadIdx.x;
    const int wv = tid >> 6, lane = tid & 63;
    int u = blockIdx.x * DW + wv;               // 172*4 = 688 waves
    if (u > 686) return;
    if (u == 686) {                             // ---- prior chain ----
        int l = lane;
        bool has2 = (l + 64) < OO;
        float pa = p0arr[l];
        float pb = has2 ? p0arr[l + 64] : -1e30f;
        auto norm = [&]() {
            pa = fminf(fmaxf(pa, -5.0f), 0.0f);
            if (has2) pb = fminf(fmaxf(pb, -5.0f), 0.0f);
            float mx = has2 ? fmaxf(pa, pb) : pa;
            #pragma unroll
            for (int s = 32; s > 0; s >>= 1) mx = fmaxf(mx, __shfl_xor(mx, s, 64));
            float smv = expf(pa - mx) + (has2 ? expf(pb - mx) : 0.0f);
            #pragma unroll
            for (int s = 32; s > 0; s >>= 1) smv += __shfl_xor(smv, s, 64);
            float lse = logf(smv) + mx;
            pa -= lse;
            if (has2) pb -= lse;
        };
        norm();
        for (int t = 0; t < TT; ++t) {
            float eta = 0.001f / (float)(t + 1);
            float wma = (float)cntg[t * OO + l] * (1.0f / 256.0f);
            pa += eta * ((-5.0f * pa - 1.0f) * wma - (1.0f - wma));
            if (has2) {
                float wmb = (float)cntg[t * OO + l + 64] * (1.0f / 256.0f);
                pb += eta * ((-5.0f * pb - 1.0f) * wmb - (1.0f - wmb));
            }
            norm();
        }
        outp[l] = pa;
        if (has2) outp[l + 64] = pb;
        return;
    }

    const int pg = u % 98, og = u / 98;         // og 0..6
    const int p0 = pg * 8, o0 = og * 16;
    const int pl = lane & 7, ol = lane >> 3;    // 8 pl x 8 ol
    const int oA = o0 + ol, oB = oA + 8;
    const int i0 = p0 + pl, i1 = i0 + PAIRS;
    const bool actA = (oA < OO), actB = (oB < OO);

    // rows GLD: lane -> u64 pair (e0, e0+1), e = k*8+pl; 1 GLD fills 2 slots
    const int e0 = (lane & 31) * 2;
    const int wk0 = e0 >> 3, wpl0 = e0 & 7;
    const u64* rowg = bitB + (size_t)((wk0 & 3) * INN + (wk0 >> 2) * PAIRS
                                      + p0 + wpl0);
    const int lw = lane & 31;
    const u64* wpg = (lane < 32) ? winbits : postbits;
    const bool wpact = (o0 + (lw >> 1)) < OO;
    const bool cntact = (lane < 8) && ((o0 + (lane & 3) * 4) < OO);

    auto issueG = [&](int G) {
        int r0 = 2 * G;
        {   // rows: slots r0&31, (r0&31)+1 (1 GLD, 64 lanes, 1 KB)
            int rr = r0 + (lane >> 5); if (rr > TT - 1) rr = TT - 1;
            GLD16(rowg + (size_t)rr * ROWSTRIDE,
                  (las_p)&sm.rows[wv][r0 & 31][0]);
        }
        {   // wp slot r0
            int rr = r0; if (rr > TT - 1) rr = TT - 1;
            if (wpact)
                GLD16(wpg + ((size_t)rr * OO + o0) * 4 + 2 * lw,
                      (las_p)&sm.wp[wv][r0 & 15][0]);
        }
        {   // wp slot r0+1
            int rr = r0 + 1; if (rr > TT - 1) rr = TT - 1;
            if (wpact)
                GLD16(wpg + ((size_t)rr * OO + o0) * 4 + 2 * lw,
                      (las_p)&sm.wp[wv][(r0 + 1) & 15][0]);
        }
        {   // cnt: slots r0&15, +1 (8 lanes, 128 B)
            if (cntact) {
                int rr = r0 + (lane >> 2); if (rr > TT - 1) rr = TT - 1;
                GLD16(cntg + (size_t)rr * OO + o0 + (lane & 3) * 4,
                      (las_p)&sm.cntR[wv][r0 & 15][0]);
            }
        }
    };

    // chain init (clamp + pairwise lse)
    float aA = actA ? L0[(size_t)i0 * OO + oA] : -1.0f;
    float bA = actA ? L0[(size_t)i1 * OO + oA] : -1.0f;
    float aB = actB ? L0[(size_t)i0 * OO + oB] : -1.0f;
    float bB = actB ? L0[(size_t)i1 * OO + oB] : -1.0f;
    {
        aA = fminf(fmaxf(aA, -5.0f), 0.0f);
        bA = fminf(fmaxf(bA, -5.0f), 0.0f);
        float m = fmaxf(aA, bA), mn = fminf(aA, bA);
        float lse = __logf(1.0f + __expf(mn - m)) + m;
        aA -= lse; bA -= lse;
        aB = fminf(fmaxf(aB, -5.0f), 0.0f);
        bB = fminf(fmaxf(bB, -5.0f), 0.0f);
        float m2 = fmaxf(aB, bB), mn2 = fminf(aB, bB);
        float lse2 = __logf(1.0f + __expf(mn2 - m2)) + m2;
        aB -= lse2; bB -= lse2;
    }

    auto chainstep = [&](int t, int sp) {
        int s = t & 15;
        const u64* wpS = &sm.wp[wv][s][0];
        const u64* P = sm.potC[wv][sp][pl];
        const u64* Lt = sm.ltpC[wv][sp][pl];
        u64 P0 = P[0], P1 = P[1], P2 = P[2], P3 = P[3];
        u64 P4 = P[4], P5 = P[5], P6 = P[6], P7 = P[7];
        u64 Q0 = Lt[0], Q1 = Lt[1], Q2 = Lt[2], Q3 = Lt[3];
        u64 Q4 = Lt[4], Q5 = Lt[5], Q6 = Lt[6], Q7 = Lt[7];
        float eta = 0.001f / (float)(t + 1);
        {
            u64 W0 = wpS[ol*4+0], W1 = wpS[ol*4+1], W2 = wpS[ol*4+2], W3 = wpS[ol*4+3];
            u64 S0 = wpS[64+ol*4+0], S1 = wpS[64+ol*4+1], S2 = wpS[64+ol*4+2], S3 = wpS[64+ol*4+3];
            float cw = (float)sm.cntR[wv][s][ol];
            float lt0 = (float)(__popcll(Q0&W0)+__popcll(Q1&W1)+__popcll(Q2&W2)+__popcll(Q3&W3));
            float lt1 = (float)(__popcll(Q4&W0)+__popcll(Q5&W1)+__popcll(Q6&W2)+__popcll(Q7&W3));
            float pp0 = (float)(__popcll(P0&S0)+__popcll(P1&S1)+__popcll(P2&S2)+__popcll(P3&S3));
            float pp1 = (float)(__popcll(P4&S0)+__popcll(P5&S1)+__popcll(P6&S2)+__popcll(P7&S3));
            float dw0 = (5.0f*__expf(-aA) - 1.0f)*(lt0*(1.0f/256.0f))
                      + (cw - lt0 - pp0)*(1.0f/256.0f);
            float dw1 = (5.0f*__expf(-bA) - 1.0f)*(lt1*(1.0f/256.0f))
                      + (cw - lt1 - pp1)*(1.0f/256.0f);
            aA += eta*dw0; bA += eta*dw1;
            aA = fminf(fmaxf(aA,-5.0f),0.0f);
            bA = fminf(fmaxf(bA,-5.0f),0.0f);
            float m = fmaxf(aA,bA), mn = fminf(aA,bA);
            float lse = __logf(1.0f + __expf(mn-m)) + m;
            aA -= lse; bA -= lse;
        }
        {
            u64 W0 = wpS[(ol+8)*4+0], W1 = wpS[(ol+8)*4+1], W2 = wpS[(ol+8)*4+2], W3 = wpS[(ol+8)*4+3];
            u64 S0 = wpS[64+(ol+8)*4+0], S1 = wpS[64+(ol+8)*4+1], S2 = wpS[64+(ol+8)*4+2], S3 = wpS[64+(ol+8)*4+3];
            float cw = (float)sm.cntR[wv][s][ol+8];
            float lt0 = (float)(__popcll(Q0&W0)+__popcll(Q1&W1)+__popcll(Q2&W2)+__popcll(Q3&W3));
            float lt1 = (float)(__popcll(Q4&W0)+__popcll(Q5&W1)+__popcll(Q6&W2)+__popcll(Q7&W3));
            float pp0 = (float)(__popcll(P0&S0)+__popcll(P1&S1)+__popcll(P2&S2)+__popcll(P3&S3));
            float pp1 = (float)(__popcll(P4&S0)+__popcll(P5&S1)+__popcll(P6&S2)+__popcll(P7&S3));
            float dw0 = (5.0f*__expf(-aB) - 1.0f)*(lt0*(1.0f/256.0f))
                      + (cw - lt0 - pp0)*(1.0f/256.0f);
            float dw1 = (5.0f*__expf(-bB) - 1.0f)*(lt1*(1.0f/256.0f))
                      + (cw - lt1 - pp1)*(1.0f/256.0f);
            aB += eta*dw0; bB += eta*dw1;
            aB = fminf(fmaxf(aB,-5.0f),0.0f);
            bB = fminf(fmaxf(bB,-5.0f),0.0f);
            float m = fmaxf(aB,bB), mn = fminf(aB,bB);
            float lse = __logf(1.0f + __expf(mn-m)) + m;
            aB -= lse; bB -= lse;
        }
    };

    issueG(0); issueG(1); issueG(2); issueG(3);
    for (int I = 0; I < 100; ++I) {
        issueG(I + 4);
        asm volatile("s_waitcnt vmcnt(16)" ::: "memory");  // group I resident
        int b0 = 2 * I;
        u64 com = 0;
        #pragma unroll
        for (int j = 8; j >= 0; --j) {
            int r = b0 - j; r = (r < 0) ? 0 : r;
            com |= sm.rows[wv][r & 31][lane];
        }
        int r9 = b0 - 9;   r9 = (r9 < 0) ? 0 : r9;
        int r10 = b0 - 10; r10 = (r10 < 0) ? 0 : r10;
        u64 v9  = sm.rows[wv][r9 & 31][lane];
        u64 v10 = sm.rows[wv][r10 & 31][lane];
        u64 vt2 = sm.rows[wv][(b0 + 1) & 31][lane];
        u64 pot1 = com | v9;
        u64 pot2 = com | vt2;
        sm.potC[wv][0][lane & 7][lane >> 3] = pot1;
        sm.potC[wv][1][lane & 7][lane >> 3] = pot2;
        sm.ltpC[wv][0][lane & 7][lane >> 3] = pot1 | v10;
        sm.ltpC[wv][1][lane & 7][lane >> 3] = pot2 | v9;
        asm volatile("s_waitcnt lgkmcnt(0)" ::: "memory");  // cross-lane publish
        chainstep(b0, 0);
        chainstep(b0 + 1, 1);
    }
    if (actA) {
        outL[(size_t)i0 * OO + oA] = aA;
        outL[(size_t)i1 * OO + oA] = bA;
    }
    if (actB) {
        outL[(size_t)i0 * OO + oB] = aB;
        outL[(size_t)i1 * OO + oB] = bB;
    }
}

extern "C" void kernel_launch(void* const* d_in, const int* in_sizes, int n_in,
                              void* d_out, int out_size, void* d_ws, size_t ws_size,
                              hipStream_t stream) {
    const int*   x  = (const int*)d_in[0];
    const float* L0 = (const float*)d_in[1];
    const float* p0 = (const float*)d_in[2];
    float* out = (float*)d_out;

    char* ws = (char*)d_ws;
    size_t off = 0;
    auto alloc = [&](size_t bytes) -> void* {
        off = (off + 255) & ~(size_t)255;
        void* p = ws + off;
        off += bytes;
        return p;
    };
    uint8_t*  widx     = (uint8_t*) alloc((size_t)TT * BB);
    uint32_t* cntg     = (uint32_t*)alloc((size_t)TT * OO * 4);
    u64*      winbits  = (u64*)     alloc((size_t)TT * OO * 4 * 8);
    u64*      postbits = (u64*)     alloc((size_t)TT * OO * 4 * 8);
    u64*      bitB     = (u64*)     alloc((size_t)TT * 4 * INN * 8);
    (void)ws_size;

    hipLaunchKernelGGL(k_packwin, dim3(300), dim3(512), 0, stream, x, bitB, widx);
    hipLaunchKernelGGL(k_fwpost,  dim3(100), dim3(256), 0, stream,
                       widx, winbits, postbits, cntg);
    hipLaunchKernelGGL(k_chains,  dim3(172), dim3(256), 0, stream,
                       L0, p0, bitB, winbits, postbits, cntg,
                       out, out + (size_t)INN * OO);
}